// Round 1
// 515.692 us; speedup vs baseline: 1.0013x; 1.0013x over previous
//
#include <hip/hip_runtime.h>
#include <math.h>

#define D_MODEL 1024
#define NHEAD   16
#define HDIM    64
#define SEQ     2048
#define BATCH   4
#define NROWS   (BATCH*SEQ)   // 8192

using bf16x8 = __attribute__((ext_vector_type(8))) short;
using bf16x4 = __attribute__((ext_vector_type(4))) short;
using f32x4  = __attribute__((ext_vector_type(4))) float;

__device__ __forceinline__ unsigned short f2bf(float f) {
    unsigned u = __float_as_uint(f);
    u += 0x7fffu + ((u >> 16) & 1u);
    return (unsigned short)(u >> 16);
}
__device__ __forceinline__ float bf2f(unsigned short h) {
    unsigned u = ((unsigned)h) << 16;
    return __uint_as_float(u);
}

#define ASYNC_COPY16(g, l) \
    __builtin_amdgcn_global_load_lds((__attribute__((address_space(1))) const void*)(g), \
                                     (__attribute__((address_space(3))) void*)(l), 16, 0, 0)

// ---------------- LayerNorm (LN1): one block per row of 1024 --------------------
__global__ __launch_bounds__(256) void ln_kernel(const float* __restrict__ x,
                                                 const float* __restrict__ g,
                                                 const float* __restrict__ b,
                                                 unsigned short* __restrict__ out) {
    const int row = blockIdx.x;
    const int tid = threadIdx.x;
    const float4* x4 = (const float4*)(x + (size_t)row * D_MODEL);
    float4 v = x4[tid];
    float s  = v.x + v.y + v.z + v.w;
    float sq = v.x*v.x + v.y*v.y + v.z*v.z + v.w*v.w;
    #pragma unroll
    for (int off = 32; off >= 1; off >>= 1) {
        s  += __shfl_down(s,  off, 64);
        sq += __shfl_down(sq, off, 64);
    }
    __shared__ float rs[4], rq[4];
    const int wave = tid >> 6;
    if ((tid & 63) == 0) { rs[wave] = s; rq[wave] = sq; }
    __syncthreads();
    const float tot  = rs[0] + rs[1] + rs[2] + rs[3];
    const float totq = rq[0] + rq[1] + rq[2] + rq[3];
    const float mu   = tot * (1.0f / D_MODEL);
    const float var  = totq * (1.0f / D_MODEL) - mu * mu;
    const float rstd = rsqrtf(var + 1e-5f);
    const float4 gv = ((const float4*)g)[tid];
    const float4 bv = ((const float4*)b)[tid];
    unsigned short* o = out + (size_t)row * D_MODEL + tid * 4;
    o[0] = f2bf((v.x - mu) * rstd * gv.x + bv.x);
    o[1] = f2bf((v.y - mu) * rstd * gv.y + bv.y);
    o[2] = f2bf((v.z - mu) * rstd * gv.z + bv.z);
    o[3] = f2bf((v.w - mu) * rstd * gv.w + bv.w);
}

// ------------- Weight transpose+convert: w[K][N] f32 -> wt[N][K] bf16 -----------
__global__ __launch_bounds__(256) void wt_kernel(const float* __restrict__ w,
                                                 unsigned short* __restrict__ wt,
                                                 int K, int N) {
    __shared__ float tile[32][33];
    const int n0 = blockIdx.x * 32, k0 = blockIdx.y * 32;
    const int tx = threadIdx.x & 31, ty = threadIdx.x >> 5;
    #pragma unroll
    for (int j = 0; j < 4; ++j)
        tile[ty + j * 8][tx] = w[(size_t)(k0 + ty + j * 8) * N + n0 + tx];
    __syncthreads();
    #pragma unroll
    for (int j = 0; j < 4; ++j)
        wt[(size_t)(n0 + ty + j * 8) * K + k0 + tx] = f2bf(tile[tx][ty + j * 8]);
}

// ===================== 8-phase 256x256 GEMM, BK=64 (2 K-halves of 32) ===========
// 512 threads = 8 waves (2 wm x 4 wn). Per wave: 128 rows x 64 cols = acc[8][4].
// LDS 128 KiB dynamic: 2 buffers x {A_kh0|A_kh1|B_kh0|B_kh1} of 16 KiB each.
// Per phase: ds_read frags, stage ONE 16-KiB half (2 x global_load_lds/thread),
//            s_barrier, setprio(1), 16 MFMA, setprio(0), s_barrier.
// vmcnt(6) only once per K-tile (3 half-tiles = 6 loads stay in flight across
// barriers) -- never drains to 0 in steady state (T3+T4).
// Staging targets (tile t): q0 -> B_kh1(t+1) into OTHER buffer;
//   q1 -> A_kh0(t+2), q2 -> B_kh0(t+2), q3 -> A_kh1(t+2) into CURRENT buffer.
// Each overwritten region's last LDS read completed at the previous phase's
// trailing barrier (A_kh0 read q0; B_kh0 read q0+q1; A_kh1 read q2) -> no WAR.
// RAW: previous q3's vmcnt(6)+barrier guarantees the whole next tile landed.
// MODE 0: bias+gelu bf16 out (fc) | MODE 1: bf16 partial (split-K) | MODE 2: qkv
template<int MODE>
__global__ __launch_bounds__(512, 2) void gemm8(const unsigned short* __restrict__ A,
                                                const unsigned short* __restrict__ Bt,
                                                const float* __restrict__ bias,
                                                unsigned short* __restrict__ outp,
                                                unsigned short* __restrict__ vt_out,
                                                int M, int N, int K, int Kslice) {
    extern __shared__ __align__(16) char smem[];   // 131072 bytes

    const int tid  = threadIdx.x;
    const int lane = tid & 63;
    const int wave = __builtin_amdgcn_readfirstlane(tid >> 6);
    const int quad = lane >> 4, l16 = lane & 15;
    const int wm = wave >> 2, wn = wave & 3;
    const int m0 = blockIdx.x * 256, n0 = blockIdx.y * 256;

    int kbeg = 0, klen = K;
    if (MODE == 1) {
        kbeg = blockIdx.z * Kslice;
        klen = (blockIdx.z == (int)gridDim.z - 1) ? (K - kbeg) : Kslice;
    }
    const int nt = klen >> 6;          // K-tiles of 64 (always >= 8 here)

    // ---- staging addressing: thread covers rows r0 and r0+128, 16-B chunk p.
    // LDS fill is linear (base + tid*16); source chunk pre-swizzled p^(row&3)
    // so the read-side XOR lands on the right data (both-sides swizzle).
    const int r0  = tid >> 2;                       // 0..127
    const int gch = ((tid & 3) ^ (r0 & 3)) * 8;     // element offset in 32-elem half-row
    const unsigned short* Ag0 = A  + (size_t)(m0 + r0) * K + gch + kbeg;
    const unsigned short* Ag1 = Ag0 + (size_t)128 * K;
    const unsigned short* Bg0 = Bt + (size_t)(n0 + r0) * K + gch + kbeg;
    const unsigned short* Bg1 = Bg0 + (size_t)128 * K;
    char* ldsA = smem + tid * 16;
    char* ldsB = smem + 32768 + tid * 16;

#define STG_A(kh, tt, bb) do { const int ko_ = (tt)*64 + (kh)*32;             \
        ASYNC_COPY16(Ag0 + ko_, ldsA + (bb)*65536 + (kh)*16384);              \
        ASYNC_COPY16(Ag1 + ko_, ldsA + (bb)*65536 + (kh)*16384 + 8192); } while (0)
#define STG_B(kh, tt, bb) do { const int ko_ = (tt)*64 + (kh)*32;             \
        ASYNC_COPY16(Bg0 + ko_, ldsB + (bb)*65536 + (kh)*16384);              \
        ASYNC_COPY16(Bg1 + ko_, ldsB + (bb)*65536 + (kh)*16384 + 8192); } while (0)

    // ---- read-side fragment bases (chunk XOR-swizzled; conflict-free b128)
    const int coff = (quad ^ (l16 & 3)) * 16;
    const char* rdA = smem + (wm * 128 + l16) * 64 + coff;           // +buf*65536 +kh*16384 +i*1024
    const char* rdB = smem + 32768 + (wn * 64 + l16) * 64 + coff;    // +buf*65536 +kh*16384 +j*1024

    f32x4 acc[8][4] = {};

    // ---- prologue: tile0 full + 3 halves of tile1; keep 6 loads in flight
    STG_A(0, 0, 0); STG_B(0, 0, 0); STG_A(1, 0, 0); STG_B(1, 0, 0);
    STG_A(0, 1, 1); STG_B(0, 1, 1); STG_A(1, 1, 1);
    asm volatile("s_waitcnt vmcnt(6)\n\ts_barrier" ::: "memory");

    for (int t = 0; t < nt; ++t) {
        const int cur = t & 1;
        const char* bA = rdA + cur * 65536;
        const char* bB = rdB + cur * 65536;
        bf16x8 a[8], b0, b1;

        // ---------- phase q0: kh0, N-frags {0,1} ----------
        #pragma unroll
        for (int i = 0; i < 8; ++i) a[i] = *(const bf16x8*)(bA + i * 1024);
        b0 = *(const bf16x8*)(bB);
        b1 = *(const bf16x8*)(bB + 1024);
        if (t + 1 < nt) STG_B(1, t + 1, cur ^ 1);
        asm volatile("s_barrier" ::: "memory");
        __builtin_amdgcn_s_setprio(1);
        #pragma unroll
        for (int i = 0; i < 8; ++i) {
            acc[i][0] = __builtin_amdgcn_mfma_f32_16x16x32_bf16(a[i], b0, acc[i][0], 0, 0, 0);
            acc[i][1] = __builtin_amdgcn_mfma_f32_16x16x32_bf16(a[i], b1, acc[i][1], 0, 0, 0);
        }
        __builtin_amdgcn_s_setprio(0);
        asm volatile("s_barrier" ::: "memory");

        // ---------- phase q1: kh0, N-frags {2,3} (A regs reused) ----------
        b0 = *(const bf16x8*)(bB + 2048);
        b1 = *(const bf16x8*)(bB + 3072);
        if (t + 2 < nt) STG_A(0, t + 2, cur);
        asm volatile("s_barrier" ::: "memory");
        __builtin_amdgcn_s_setprio(1);
        #pragma unroll
        for (int i = 0; i < 8; ++i) {
            acc[i][2] = __builtin_amdgcn_mfma_f32_16x16x32_bf16(a[i], b0, acc[i][2], 0, 0, 0);
            acc[i][3] = __builtin_amdgcn_mfma_f32_16x16x32_bf16(a[i], b1, acc[i][3], 0, 0, 0);
        }
        __builtin_amdgcn_s_setprio(0);
        asm volatile("s_barrier" ::: "memory");

        // ---------- phase q2: kh1, N-frags {0,1} ----------
        #pragma unroll
        for (int i = 0; i < 8; ++i) a[i] = *(const bf16x8*)(bA + 16384 + i * 1024);
        b0 = *(const bf16x8*)(bB + 16384);
        b1 = *(const bf16x8*)(bB + 16384 + 1024);
        if (t + 2 < nt) STG_B(0, t + 2, cur);
        asm volatile("s_barrier" ::: "memory");
        __builtin_amdgcn_s_setprio(1);
        #pragma unroll
        for (int i = 0; i < 8; ++i) {
            acc[i][0] = __builtin_amdgcn_mfma_f32_16x16x32_bf16(a[i], b0, acc[i][0], 0, 0, 0);
            acc[i][1] = __builtin_amdgcn_mfma_f32_16x16x32_bf16(a[i], b1, acc[i][1], 0, 0, 0);
        }
        __builtin_amdgcn_s_setprio(0);
        asm volatile("s_barrier" ::: "memory");

        // ---------- phase q3: kh1, N-frags {2,3} ----------
        b0 = *(const bf16x8*)(bB + 16384 + 2048);
        b1 = *(const bf16x8*)(bB + 16384 + 3072);
        if (t + 2 < nt) STG_A(1, t + 2, cur);
        asm volatile("s_barrier" ::: "memory");
        __builtin_amdgcn_s_setprio(1);
        #pragma unroll
        for (int i = 0; i < 8; ++i) {
            acc[i][2] = __builtin_amdgcn_mfma_f32_16x16x32_bf16(a[i], b0, acc[i][2], 0, 0, 0);
            acc[i][3] = __builtin_amdgcn_mfma_f32_16x16x32_bf16(a[i], b1, acc[i][3], 0, 0, 0);
        }
        __builtin_amdgcn_s_setprio(0);
        // end-of-tile wait: next tile fully landed, 3 half-tiles stay in flight
        if (t + 2 < nt) asm volatile("s_waitcnt vmcnt(6)\n\ts_barrier" ::: "memory");
        else            asm volatile("s_waitcnt vmcnt(0)\n\ts_barrier" ::: "memory");
    }
#undef STG_A
#undef STG_B

    if (MODE == 0) {
        #pragma unroll
        for (int i = 0; i < 8; ++i)
          #pragma unroll
          for (int j = 0; j < 4; ++j)
            #pragma unroll
            for (int r = 0; r < 4; ++r) {
                const int row = m0 + wm * 128 + i * 16 + quad * 4 + r;
                const int col = n0 + wn * 64 + j * 16 + l16;
                float v = acc[i][j][r] + bias[col];
                const float u = 0.7978845608028654f * (v + 0.044715f * v * v * v);
                const float e = __expf(2.0f * u);
                v = 0.5f * v * (2.0f - 2.0f / (e + 1.0f));
                outp[(size_t)row * N + col] = f2bf(v);
            }
    } else if (MODE == 1) {
        unsigned short* outb = outp + (size_t)blockIdx.z * M * N;
        #pragma unroll
        for (int i = 0; i < 8; ++i)
          #pragma unroll
          for (int j = 0; j < 4; ++j)
            #pragma unroll
            for (int r = 0; r < 4; ++r) {
                const int row = m0 + wm * 128 + i * 16 + quad * 4 + r;
                const int col = n0 + wn * 64 + j * 16 + l16;
                outb[(size_t)row * N + col] = f2bf(acc[i][j][r]);
            }
    } else {
        if (n0 < 2048) {
            const float sc = (n0 < 1024) ? 0.125f : 1.0f;   // 256-tile never straddles 1024
            #pragma unroll
            for (int i = 0; i < 8; ++i)
              #pragma unroll
              for (int j = 0; j < 4; ++j)
                #pragma unroll
                for (int r = 0; r < 4; ++r) {
                    const int row = m0 + wm * 128 + i * 16 + quad * 4 + r;
                    const int col = n0 + wn * 64 + j * 16 + l16;
                    outp[(size_t)row * 2048 + col] = f2bf(acc[i][j][r] * sc);
                }
        } else {
            #pragma unroll
            for (int i = 0; i < 8; ++i)
              #pragma unroll
              for (int j = 0; j < 4; ++j) {
                    const int dv  = n0 - 2048 + wn * 64 + j * 16 + l16;
                    const int tok = m0 + wm * 128 + i * 16 + quad * 4;
                    ushort4 pk;
                    pk.x = f2bf(acc[i][j][0]); pk.y = f2bf(acc[i][j][1]);
                    pk.z = f2bf(acc[i][j][2]); pk.w = f2bf(acc[i][j][3]);
                    *(ushort4*)(vt_out + (size_t)dv * NROWS + tok) = pk;
                }
        }
    }
}

// ------- fused w_o reduce: res1 = x + p0..p{NP-1} -> out(f32); LN2 -> lnout -----
template<int NP>
__global__ __launch_bounds__(256) void reduce_wo_ln2(const float* __restrict__ x,
                                                     const unsigned short* __restrict__ pw,
                                                     const float* __restrict__ g,
                                                     const float* __restrict__ bb,
                                                     float* __restrict__ out,
                                                     unsigned short* __restrict__ lnout) {
    const int row = blockIdx.x;
    const int tid = threadIdx.x;
    const size_t base = (size_t)row * D_MODEL + tid * 4;
    const size_t stride = (size_t)NROWS * D_MODEL;
    float4 v = *(const float4*)(x + base);
    #pragma unroll
    for (int z = 0; z < NP; ++z) {
        ushort4 a = *(const ushort4*)(pw + z * stride + base);
        v.x += bf2f(a.x); v.y += bf2f(a.y); v.z += bf2f(a.z); v.w += bf2f(a.w);
    }
    *(float4*)(out + base) = v;

    float s  = v.x + v.y + v.z + v.w;
    float sq = v.x*v.x + v.y*v.y + v.z*v.z + v.w*v.w;
    #pragma unroll
    for (int off = 32; off >= 1; off >>= 1) {
        s  += __shfl_down(s,  off, 64);
        sq += __shfl_down(sq, off, 64);
    }
    __shared__ float rs[4], rq[4];
    const int wave = tid >> 6;
    if ((tid & 63) == 0) { rs[wave] = s; rq[wave] = sq; }
    __syncthreads();
    const float tot  = rs[0] + rs[1] + rs[2] + rs[3];
    const float totq = rq[0] + rq[1] + rq[2] + rq[3];
    const float mu   = tot * (1.0f / D_MODEL);
    const float var  = totq * (1.0f / D_MODEL) - mu * mu;
    const float rstd = rsqrtf(var + 1e-5f);
    const float4 gv = ((const float4*)g)[tid];
    const float4 bv = ((const float4*)bb)[tid];
    unsigned short* o = lnout + (size_t)row * D_MODEL + tid * 4;
    o[0] = f2bf((v.x - mu) * rstd * gv.x + bv.x);
    o[1] = f2bf((v.y - mu) * rstd * gv.y + bv.y);
    o[2] = f2bf((v.z - mu) * rstd * gv.z + bv.z);
    o[3] = f2bf((v.w - mu) * rstd * gv.w + bv.w);
}

// ------------- proj split-K reduce: out += bias + p0..p{NP-1} -------------------
template<int NP>
__global__ __launch_bounds__(256) void reduce_kernel(float* __restrict__ out,
                                                     const unsigned short* __restrict__ pp,
                                                     const float* __restrict__ bias) {
    const int row = blockIdx.x;
    const int c0 = threadIdx.x * 4;
    const size_t base = (size_t)row * D_MODEL + c0;
    const size_t stride = (size_t)NROWS * D_MODEL;
    float4 o = *(float4*)(out + base);
    const float4 bs = *(const float4*)(bias + c0);
    o.x += bs.x; o.y += bs.y; o.z += bs.z; o.w += bs.w;
    #pragma unroll
    for (int z = 0; z < NP; ++z) {
        ushort4 a = *(const ushort4*)(pp + z * stride + base);
        o.x += bf2f(a.x); o.y += bf2f(a.y); o.z += bf2f(a.z); o.w += bf2f(a.w);
    }
    *(float4*)(out + base) = o;
}

// ---------------- Flash attention, causal, balanced (paired 128-q tiles) --------
__global__ __launch_bounds__(256) void attn_kernel(const unsigned short* __restrict__ qk,
                                                   const unsigned short* __restrict__ VT,
                                                   unsigned short* __restrict__ y) {
    __shared__ __align__(16) unsigned short Qs[128 * 64];
    __shared__ __align__(16) unsigned short Ks[64 * 64];
    __shared__ __align__(16) unsigned short Vs[80 * 64];
    __shared__ __align__(16) unsigned short Ps[128 * 68];

    const int tid  = threadIdx.x;
    const int lane = tid & 63, w = tid >> 6;
    const int quad = lane >> 4, l16 = lane & 15;
    const int s7   = l16 & 7;
    const int pc0  = (quad ^ s7) * 8;
    const int pc1  = ((quad + 4) ^ s7) * 8;
    const int srow = tid >> 3, sp = tid & 7;

    const int pairidx = blockIdx.x;
    const int bh = blockIdx.y;
    const int b = bh >> 4, h = bh & 15;
    const size_t rowbase = (size_t)b * SEQ;
    const unsigned short* Qbase = qk + h * 64;
    const unsigned short* Kbase = qk + 1024 + h * 64;
    const unsigned short* Vbase = VT + (size_t)(h * 64) * NROWS + b * SEQ;

    #pragma unroll
    for (int e = 0; e < 4; ++e) {
        const int off = tid * 4 + e;
        Vs[4096 + off] = (off < 64) ? (unsigned short)0x3F80 : (unsigned short)0;
    }

    for (int phase = 0; phase < 2; ++phase) {
        const int Q = phase ? pairidx : (15 - pairidx);
        const int nkt = 2 * Q + 2;
        const int qg0 = Q * 128;

        #pragma unroll
        for (int i = 0; i < 4; ++i) {
            const int row = i * 32 + srow;
            const int c = sp ^ (row & 7);
            ASYNC_COPY16(Qbase + (rowbase + qg0 + row) * 2048 + c * 8,
                         (char*)Qs + i * 4096 + tid * 16);
        }
        __syncthreads();

        bf16x8 aq[2][2];
        #pragma unroll
        for (int sub = 0; sub < 2; ++sub) {
            const int qrow = sub * 64 + w * 16 + l16;
            aq[sub][0] = *(const bf16x8*)&Qs[qrow * 64 + pc0];
            aq[sub][1] = *(const bf16x8*)&Qs[qrow * 64 + pc1];
        }

        f32x4 o[2][5] = {};

        for (int kt = 0; kt < nkt; ++kt) {
            #pragma unroll
            for (int i = 0; i < 2; ++i) {
                const int row = i * 32 + srow;
                const int c = sp ^ (row & 7);
                ASYNC_COPY16(Kbase + (rowbase + kt * 64 + row) * 2048 + c * 8,
                             (char*)Ks + i * 4096 + tid * 16);
                ASYNC_COPY16(Vbase + (size_t)row * NROWS + kt * 64 + c * 8,
                             (char*)Vs + i * 4096 + tid * 16);
            }
            __syncthreads();

            bf16x8 bk[4][2];
            #pragma unroll
            for (int cb = 0; cb < 4; ++cb) {
                const int krow = cb * 16 + l16;
                bk[cb][0] = *(const bf16x8*)&Ks[krow * 64 + pc0];
                bk[cb][1] = *(const bf16x8*)&Ks[krow * 64 + pc1];
            }

            #pragma unroll
            for (int sub = 0; sub < 2; ++sub) {
                if (kt > 2 * Q + sub) continue;
                f32x4 s[4] = {};
                #pragma unroll
                for (int cb = 0; cb < 4; ++cb) {
                    s[cb] = __builtin_amdgcn_mfma_f32_16x16x32_bf16(aq[sub][0], bk[cb][0], s[cb], 0, 0, 0);
                    s[cb] = __builtin_amdgcn_mfma_f32_16x16x32_bf16(aq[sub][1], bk[cb][1], s[cb], 0, 0, 0);
                }
                const int prow0 = sub * 64 + w * 16 + quad * 4;
                if (kt == 2 * Q + sub) {
                    const int qg = qg0 + prow0;
                    const int kg = kt * 64 + l16;
                    #pragma unroll
                    for (int cb = 0; cb < 4; ++cb)
                        #pragma unroll
                        for (int r = 0; r < 4; ++r) {
                            const float e = __expf(s[cb][r]);
                            const float pv = (kg + cb * 16 > qg + r) ? 0.0f : e;
                            Ps[(prow0 + r) * 68 + cb * 16 + l16] = f2bf(pv);
                        }
                } else {
                    #pragma unroll
                    for (int cb = 0; cb < 4; ++cb)
                        #pragma unroll
                        for (int r = 0; r < 4; ++r)
                            Ps[(prow0 + r) * 68 + cb * 16 + l16] = f2bf(__expf(s[cb][r]));
                }
            }
            __syncthreads();

            bf16x8 bv[5][2];
            #pragma unroll
            for (int db = 0; db < 5; ++db) {
                const int vrow = db * 16 + l16;
                bv[db][0] = *(const bf16x8*)&Vs[vrow * 64 + pc0];
                bv[db][1] = *(const bf16x8*)&Vs[vrow * 64 + pc1];
            }
            #pragma unroll
            for (int sub = 0; sub < 2; ++sub) {
                if (kt > 2 * Q + sub) continue;
                const unsigned short* pb = &Ps[(sub * 64 + w * 16 + l16) * 68];
                bf16x8 ap0, ap1;
                *(bf16x4*)&ap0       = *(const bf16x4*)(pb + quad * 8);
                *((bf16x4*)&ap0 + 1) = *(const bf16x4*)(pb + quad * 8 + 4);
                *(bf16x4*)&ap1       = *(const bf16x4*)(pb + 32 + quad * 8);
                *((bf16x4*)&ap1 + 1) = *(const bf16x4*)(pb + 32 + quad * 8 + 4);
                #pragma unroll
                for (int db = 0; db < 5; ++db) {
                    o[sub][db] = __builtin_amdgcn_mfma_f32_16x16x32_bf16(ap0, bv[db][0], o[sub][db], 0, 0, 0);
                    o[sub][db] = __builtin_amdgcn_mfma_f32_16x16x32_bf16(ap1, bv[db][1], o[sub][db], 0, 0, 0);
                }
            }
            __syncthreads();
        }

        #pragma unroll
        for (int sub = 0; sub < 2; ++sub)
            #pragma unroll
            for (int r = 0; r < 4; ++r) {
                const float lsum = __shfl(o[sub][4][r], lane & 48);
                const float rinv = 1.0f / lsum;
                const int trow = qg0 + sub * 64 + w * 16 + quad * 4 + r;
                unsigned short* yp = y + (rowbase + trow) * (size_t)D_MODEL + h * 64 + l16;
                #pragma unroll
                for (int db = 0; db < 4; ++db)
                    yp[db * 16] = f2bf(o[sub][db][r] * rinv);
            }
    }
}

extern "C" void kernel_launch(void* const* d_in, const int* in_sizes, int n_in,
                              void* d_out, int out_size, void* d_ws, size_t ws_size,
                              hipStream_t stream) {
    (void)in_sizes; (void)n_in; (void)out_size; (void)ws_size;
    const float* x      = (const float*)d_in[0];
    const float* w_attn = (const float*)d_in[1];
    const float* w_o    = (const float*)d_in[2];
    const float* ln1_g  = (const float*)d_in[3];
    const float* ln1_b  = (const float*)d_in[4];
    const float* ln2_g  = (const float*)d_in[5];
    const float* ln2_b  = (const float*)d_in[6];
    const float* w_fc   = (const float*)d_in[7];
    const float* b_fc   = (const float*)d_in[8];
    const float* w_proj = (const float*)d_in[9];
    const float* b_proj = (const float*)d_in[10];
    float* out = (float*)d_out;

    static bool attr_set = false;
    if (!attr_set) {
        hipFuncSetAttribute(reinterpret_cast<const void*>(&gemm8<0>),
                            hipFuncAttributeMaxDynamicSharedMemorySize, 131072);
        hipFuncSetAttribute(reinterpret_cast<const void*>(&gemm8<1>),
                            hipFuncAttributeMaxDynamicSharedMemorySize, 131072);
        hipFuncSetAttribute(reinterpret_cast<const void*>(&gemm8<2>),
                            hipFuncAttributeMaxDynamicSharedMemorySize, 131072);
        attr_set = true;
    }

    char* ws = (char*)d_ws;
    const size_t MiB = 1048576;
    // Memory map (MiB), phase-ordered:
    //  phase1: ln_buf@0..16 | qkbuf@16..48 | VTbuf@48..64 | wt_attn@64..70 | wt_o@126..128
    //  phase2 (post-attn): pw@16..48 (2x16)
    //  phase3 (post-reduce_wo): wt_fc@48..56 | wt_proj@56..64 | hbuf@64..128
    //  phase4 (post-fc): pp@0..32 (2x16)
    unsigned short* ln_buf  = (unsigned short*)ws;
    unsigned short* qkbuf   = (unsigned short*)(ws + 16 * MiB);
    unsigned short* VTbuf   = (unsigned short*)(ws + 48 * MiB);
    unsigned short* wt_attn = (unsigned short*)(ws + 64 * MiB);
    unsigned short* hbuf    = (unsigned short*)(ws + 64 * MiB);
    unsigned short* wt_o    = (unsigned short*)(ws + 126 * MiB);
    unsigned short* pw      = (unsigned short*)(ws + 16 * MiB);   // 2 x 16 MiB
    unsigned short* wt_fc   = (unsigned short*)(ws + 48 * MiB);
    unsigned short* wt_proj = (unsigned short*)(ws + 56 * MiB);
    unsigned short* pp      = (unsigned short*)ws;                // 2 x 16 MiB

    wt_kernel<<<dim3(3072 / 32, 1024 / 32), 256, 0, stream>>>(w_attn, wt_attn, 1024, 3072);
    wt_kernel<<<dim3(1024 / 32, 1024 / 32), 256, 0, stream>>>(w_o, wt_o, 1024, 1024);

    ln_kernel<<<NROWS, 256, 0, stream>>>(x, ln1_g, ln1_b, ln_buf);

    // merged QKV (256x256 8-phase): Q(scaled)/K -> qkbuf, V -> VTbuf (transposed)
    gemm8<2><<<dim3(NROWS / 256, 3072 / 256), 512, 131072, stream>>>(
        ln_buf, wt_attn, nullptr, qkbuf, VTbuf, NROWS, 3072, 1024, 0);

    attn_kernel<<<dim3(8, BATCH * NHEAD), 256, 0, stream>>>(qkbuf, VTbuf, ln_buf);

    // w_o: split-K=2 partials (256x256 8-phase) -> 256 blocks = 1/CU exactly
    gemm8<1><<<dim3(NROWS / 256, 1024 / 256, 2), 512, 131072, stream>>>(
        ln_buf, wt_o, nullptr, pw, nullptr, NROWS, 1024, 1024, 512);
    // res1 = x + sum(pw) -> d_out ; LN2(res1) -> ln_buf
    reduce_wo_ln2<2><<<NROWS, 256, 0, stream>>>(x, pw, ln2_g, ln2_b, out, ln_buf);

    wt_kernel<<<dim3(4096 / 32, 1024 / 32), 256, 0, stream>>>(w_fc, wt_fc, 1024, 4096);
    wt_kernel<<<dim3(1024 / 32, 4096 / 32), 256, 0, stream>>>(w_proj, wt_proj, 4096, 1024);

    // fc: 256x256 8-phase, gelu+bias fused (grid 512 = exactly 2 rounds at 1/CU)
    gemm8<0><<<dim3(NROWS / 256, 4096 / 256), 512, 131072, stream>>>(
        ln_buf, wt_fc, b_fc, hbuf, nullptr, NROWS, 4096, 1024, 0);

    // proj: 256x256 8-phase, split-K=2 (2048 each), then reduce
    gemm8<1><<<dim3(NROWS / 256, 1024 / 256, 2), 512, 131072, stream>>>(
        hbuf, wt_proj, nullptr, pp, nullptr, NROWS, 1024, 4096, 2048);
    reduce_kernel<2><<<NROWS, 256, 0, stream>>>(out, pp, b_proj);
}

// Round 2
// 493.130 us; speedup vs baseline: 1.0472x; 1.0458x over previous
//
#include <hip/hip_runtime.h>
#include <math.h>

#define D_MODEL 1024
#define NHEAD   16
#define HDIM    64
#define SEQ     2048
#define BATCH   4
#define NROWS   (BATCH*SEQ)   // 8192

using bf16x8 = __attribute__((ext_vector_type(8))) short;
using bf16x4 = __attribute__((ext_vector_type(4))) short;
using f32x4  = __attribute__((ext_vector_type(4))) float;

__device__ __forceinline__ unsigned short f2bf(float f) {
    unsigned u = __float_as_uint(f);
    u += 0x7fffu + ((u >> 16) & 1u);
    return (unsigned short)(u >> 16);
}
__device__ __forceinline__ float bf2f(unsigned short h) {
    unsigned u = ((unsigned)h) << 16;
    return __uint_as_float(u);
}

#define ASYNC_COPY16(g, l) \
    __builtin_amdgcn_global_load_lds((__attribute__((address_space(1))) const void*)(g), \
                                     (__attribute__((address_space(3))) void*)(l), 16, 0, 0)

// ---------------- LayerNorm (LN1): one block per row of 1024 --------------------
__global__ __launch_bounds__(256) void ln_kernel(const float* __restrict__ x,
                                                 const float* __restrict__ g,
                                                 const float* __restrict__ b,
                                                 unsigned short* __restrict__ out) {
    const int row = blockIdx.x;
    const int tid = threadIdx.x;
    const float4* x4 = (const float4*)(x + (size_t)row * D_MODEL);
    float4 v = x4[tid];
    float s  = v.x + v.y + v.z + v.w;
    float sq = v.x*v.x + v.y*v.y + v.z*v.z + v.w*v.w;
    #pragma unroll
    for (int off = 32; off >= 1; off >>= 1) {
        s  += __shfl_down(s,  off, 64);
        sq += __shfl_down(sq, off, 64);
    }
    __shared__ float rs[4], rq[4];
    const int wave = tid >> 6;
    if ((tid & 63) == 0) { rs[wave] = s; rq[wave] = sq; }
    __syncthreads();
    const float tot  = rs[0] + rs[1] + rs[2] + rs[3];
    const float totq = rq[0] + rq[1] + rq[2] + rq[3];
    const float mu   = tot * (1.0f / D_MODEL);
    const float var  = totq * (1.0f / D_MODEL) - mu * mu;
    const float rstd = rsqrtf(var + 1e-5f);
    const float4 gv = ((const float4*)g)[tid];
    const float4 bv = ((const float4*)b)[tid];
    unsigned short* o = out + (size_t)row * D_MODEL + tid * 4;
    o[0] = f2bf((v.x - mu) * rstd * gv.x + bv.x);
    o[1] = f2bf((v.y - mu) * rstd * gv.y + bv.y);
    o[2] = f2bf((v.z - mu) * rstd * gv.z + bv.z);
    o[3] = f2bf((v.w - mu) * rstd * gv.w + bv.w);
}

// ------------- Weight transpose+convert: w[K][N] f32 -> wt[N][K] bf16 -----------
__global__ __launch_bounds__(256) void wt_kernel(const float* __restrict__ w,
                                                 unsigned short* __restrict__ wt,
                                                 int K, int N) {
    __shared__ float tile[32][33];
    const int n0 = blockIdx.x * 32, k0 = blockIdx.y * 32;
    const int tx = threadIdx.x & 31, ty = threadIdx.x >> 5;
    #pragma unroll
    for (int j = 0; j < 4; ++j)
        tile[ty + j * 8][tx] = w[(size_t)(k0 + ty + j * 8) * N + n0 + tx];
    __syncthreads();
    #pragma unroll
    for (int j = 0; j < 4; ++j)
        wt[(size_t)(n0 + ty + j * 8) * K + k0 + tx] = f2bf(tile[tx][ty + j * 8]);
}

// ===================== 8-phase 256x256 GEMM, BK=64 ==============================
// 512 threads = 8 waves (2 wm x 4 wn). Per wave: 128 rows x 64 cols = acc[8][4].
// LDS layout (proven conflict-free, 0 in gemm_big): per buffer, A = [256 rows]
// [64 elem] (128 B rows), B same; physical 16-B chunk c of row r holds global
// chunk c ^ (r&7).  Read: addr = r*128 + ((quad ^ (l16&7))*16 ^ (kh*64)).
// Staging is by 16-KiB ROW-halves (A-lo/A-hi/B-lo/B-hi), 2 loads/thread each,
// linear dest (global_load_lds), source chunk pre-swizzled by (lane>>3) = row&7.
// Phase reads: q0 = A(kh0) + ALL B (B regions dead after q0);
//              q2 = A(kh1)         (A regions dead after q2).
// Stage slots: t.q0 -> A-hi(t+1) into buf^1 (fully dead);
//              t.q1 -> B-lo(t+2), t.q2 -> B-hi(t+2), t.q3 -> A-lo(t+2) into buf
// (each issued >=1 barrier after the target region's last read retired).
// End-of-tile s_waitcnt vmcnt(6): 7 halves (14 loads) outstanding -> keeps the
// 3 newest (t+2) in flight, guarantees tile t+1 fully landed. Requires nt >= 2.
// MODE 0: bias+gelu bf16 out (fc) | MODE 1: bf16 partial (split-K) | MODE 2: qkv
template<int MODE>
__global__ __launch_bounds__(512, 2) void gemm8(const unsigned short* __restrict__ A,
                                                const unsigned short* __restrict__ Bt,
                                                const float* __restrict__ bias,
                                                unsigned short* __restrict__ outp,
                                                unsigned short* __restrict__ vt_out,
                                                int M, int N, int K, int Kslice) {
    extern __shared__ __align__(16) char smem[];   // 131072 bytes

    const int tid  = threadIdx.x;
    const int lane = tid & 63;
    const int wave = __builtin_amdgcn_readfirstlane(tid >> 6);
    const int quad = lane >> 4, l16 = lane & 15;
    const int wm = wave >> 2, wn = wave & 3;
    const int m0 = blockIdx.x * 256, n0 = blockIdx.y * 256;

    int kbeg = 0, klen = K;
    if (MODE == 1) {
        kbeg = blockIdx.z * Kslice;
        klen = (blockIdx.z == (int)gridDim.z - 1) ? (K - kbeg) : Kslice;
    }
    const int nt = klen >> 6;          // K-tiles of 64 (>= 8 for all launches)

    // ---- staging: thread -> rows srow, srow+8 of a 128-row half; chunk swz
    const int srow   = wave * 16 + (lane >> 3);               // 0..127
    const int schunk = ((lane & 7) ^ (lane >> 3)) * 8;        // element offset
    const unsigned short* AgLo = A  + (size_t)(m0 + srow) * K + schunk + kbeg;
    const unsigned short* AgHi = AgLo + (size_t)128 * K;
    const unsigned short* BgLo = Bt + (size_t)(n0 + srow) * K + schunk + kbeg;
    const unsigned short* BgHi = BgLo + (size_t)128 * K;
    char* const ldst = smem + wave * 2048 + lane * 16;
    // region byte offsets within a 64-KiB buffer:
    //   A-lo 0 | A-hi 16384 | B-lo 32768 | B-hi 49152

#define STG(src, regOff, bb, ko) do {                                          \
        ASYNC_COPY16((src) + (ko),                ldst + (bb)*65536 + (regOff));        \
        ASYNC_COPY16((src) + (ko) + (size_t)8*K,  ldst + (bb)*65536 + (regOff) + 1024); \
    } while (0)

    // ---- read-side bases (8-chunk XOR swizzle, conflict-free b128)
    const int pc = (quad ^ (l16 & 7)) * 16;          // kh0; kh1 = pc ^ 64
    const char* rA = smem + (wm * 128 + l16) * 128;          // + buf*65536 + i*2048
    const char* rB = smem + 32768 + (wn * 64 + l16) * 128;   // + buf*65536 + j*2048

    f32x4 acc[8][4] = {};

    // ---- prologue: tile0 full + 3 halves of tile1 (A-hi(1) staged at t=0.q0)
    STG(BgLo, 32768, 0, 0); STG(BgHi, 49152, 0, 0);
    STG(AgLo, 0,     0, 0); STG(AgHi, 16384, 0, 0);
    STG(BgLo, 32768, 1, 64); STG(BgHi, 49152, 1, 64); STG(AgLo, 0, 1, 64);
    asm volatile("s_waitcnt vmcnt(6)\n\ts_barrier" ::: "memory");

    for (int t = 0; t < nt; ++t) {
        const int cur = t & 1;
        const char* bA = rA + cur * 65536;
        const char* bB = rB + cur * 65536;
        bf16x8 a[8], bk[8];   // bk[0..3] = kh0 frags, bk[4..7] = kh1 frags

        // ---------- q0: read A(kh0) + all B; stage A-hi(t+1) -> buf^1 ----------
        #pragma unroll
        for (int i = 0; i < 8; ++i) a[i] = *(const bf16x8*)(bA + i * 2048 + pc);
        #pragma unroll
        for (int j = 0; j < 4; ++j) {
            bk[j]     = *(const bf16x8*)(bB + j * 2048 + pc);
            bk[4 + j] = *(const bf16x8*)(bB + j * 2048 + (pc ^ 64));
        }
        if (t + 1 < nt) STG(AgHi, 16384, cur ^ 1, (t + 1) * 64);
        asm volatile("s_barrier" ::: "memory");
        __builtin_amdgcn_s_setprio(1);
        #pragma unroll
        for (int i = 0; i < 8; ++i) {
            acc[i][0] = __builtin_amdgcn_mfma_f32_16x16x32_bf16(a[i], bk[0], acc[i][0], 0, 0, 0);
            acc[i][1] = __builtin_amdgcn_mfma_f32_16x16x32_bf16(a[i], bk[1], acc[i][1], 0, 0, 0);
        }
        __builtin_amdgcn_s_setprio(0);
        asm volatile("s_barrier" ::: "memory");

        // ---------- q1: stage B-lo(t+2) -> buf ----------
        if (t + 2 < nt) STG(BgLo, 32768, cur, (t + 2) * 64);
        asm volatile("s_barrier" ::: "memory");
        __builtin_amdgcn_s_setprio(1);
        #pragma unroll
        for (int i = 0; i < 8; ++i) {
            acc[i][2] = __builtin_amdgcn_mfma_f32_16x16x32_bf16(a[i], bk[2], acc[i][2], 0, 0, 0);
            acc[i][3] = __builtin_amdgcn_mfma_f32_16x16x32_bf16(a[i], bk[3], acc[i][3], 0, 0, 0);
        }
        __builtin_amdgcn_s_setprio(0);
        asm volatile("s_barrier" ::: "memory");

        // ---------- q2: read A(kh1); stage B-hi(t+2) -> buf ----------
        #pragma unroll
        for (int i = 0; i < 8; ++i) a[i] = *(const bf16x8*)(bA + i * 2048 + (pc ^ 64));
        if (t + 2 < nt) STG(BgHi, 49152, cur, (t + 2) * 64);
        asm volatile("s_barrier" ::: "memory");
        __builtin_amdgcn_s_setprio(1);
        #pragma unroll
        for (int i = 0; i < 8; ++i) {
            acc[i][0] = __builtin_amdgcn_mfma_f32_16x16x32_bf16(a[i], bk[4], acc[i][0], 0, 0, 0);
            acc[i][1] = __builtin_amdgcn_mfma_f32_16x16x32_bf16(a[i], bk[5], acc[i][1], 0, 0, 0);
        }
        __builtin_amdgcn_s_setprio(0);
        asm volatile("s_barrier" ::: "memory");

        // ---------- q3: stage A-lo(t+2) -> buf ----------
        if (t + 2 < nt) STG(AgLo, 0, cur, (t + 2) * 64);
        asm volatile("s_barrier" ::: "memory");
        __builtin_amdgcn_s_setprio(1);
        #pragma unroll
        for (int i = 0; i < 8; ++i) {
            acc[i][2] = __builtin_amdgcn_mfma_f32_16x16x32_bf16(a[i], bk[6], acc[i][2], 0, 0, 0);
            acc[i][3] = __builtin_amdgcn_mfma_f32_16x16x32_bf16(a[i], bk[7], acc[i][3], 0, 0, 0);
        }
        __builtin_amdgcn_s_setprio(0);
        // end-of-tile: tile t+1 fully landed, 3 halves of t+2 stay in flight
        if (t + 2 < nt) asm volatile("s_waitcnt vmcnt(6)\n\ts_barrier" ::: "memory");
        else            asm volatile("s_waitcnt vmcnt(0)\n\ts_barrier" ::: "memory");
    }
#undef STG

    if (MODE == 0) {
        #pragma unroll
        for (int i = 0; i < 8; ++i)
          #pragma unroll
          for (int j = 0; j < 4; ++j)
            #pragma unroll
            for (int r = 0; r < 4; ++r) {
                const int row = m0 + wm * 128 + i * 16 + quad * 4 + r;
                const int col = n0 + wn * 64 + j * 16 + l16;
                float v = acc[i][j][r] + bias[col];
                const float u = 0.7978845608028654f * (v + 0.044715f * v * v * v);
                const float e = __expf(2.0f * u);
                v = 0.5f * v * (2.0f - 2.0f / (e + 1.0f));
                outp[(size_t)row * N + col] = f2bf(v);
            }
    } else if (MODE == 1) {
        unsigned short* outb = outp + (size_t)blockIdx.z * M * N;
        #pragma unroll
        for (int i = 0; i < 8; ++i)
          #pragma unroll
          for (int j = 0; j < 4; ++j)
            #pragma unroll
            for (int r = 0; r < 4; ++r) {
                const int row = m0 + wm * 128 + i * 16 + quad * 4 + r;
                const int col = n0 + wn * 64 + j * 16 + l16;
                outb[(size_t)row * N + col] = f2bf(acc[i][j][r]);
            }
    } else {
        if (n0 < 2048) {
            const float sc = (n0 < 1024) ? 0.125f : 1.0f;   // 256-tile never straddles 1024
            #pragma unroll
            for (int i = 0; i < 8; ++i)
              #pragma unroll
              for (int j = 0; j < 4; ++j)
                #pragma unroll
                for (int r = 0; r < 4; ++r) {
                    const int row = m0 + wm * 128 + i * 16 + quad * 4 + r;
                    const int col = n0 + wn * 64 + j * 16 + l16;
                    outp[(size_t)row * 2048 + col] = f2bf(acc[i][j][r] * sc);
                }
        } else {
            #pragma unroll
            for (int i = 0; i < 8; ++i)
              #pragma unroll
              for (int j = 0; j < 4; ++j) {
                    const int dv  = n0 - 2048 + wn * 64 + j * 16 + l16;
                    const int tok = m0 + wm * 128 + i * 16 + quad * 4;
                    ushort4 pk;
                    pk.x = f2bf(acc[i][j][0]); pk.y = f2bf(acc[i][j][1]);
                    pk.z = f2bf(acc[i][j][2]); pk.w = f2bf(acc[i][j][3]);
                    *(ushort4*)(vt_out + (size_t)dv * NROWS + tok) = pk;
                }
        }
    }
}

// ------- fused w_o reduce: res1 = x + p0..p{NP-1} -> out(f32); LN2 -> lnout -----
template<int NP>
__global__ __launch_bounds__(256) void reduce_wo_ln2(const float* __restrict__ x,
                                                     const unsigned short* __restrict__ pw,
                                                     const float* __restrict__ g,
                                                     const float* __restrict__ bb,
                                                     float* __restrict__ out,
                                                     unsigned short* __restrict__ lnout) {
    const int row = blockIdx.x;
    const int tid = threadIdx.x;
    const size_t base = (size_t)row * D_MODEL + tid * 4;
    const size_t stride = (size_t)NROWS * D_MODEL;
    float4 v = *(const float4*)(x + base);
    #pragma unroll
    for (int z = 0; z < NP; ++z) {
        ushort4 a = *(const ushort4*)(pw + z * stride + base);
        v.x += bf2f(a.x); v.y += bf2f(a.y); v.z += bf2f(a.z); v.w += bf2f(a.w);
    }
    *(float4*)(out + base) = v;

    float s  = v.x + v.y + v.z + v.w;
    float sq = v.x*v.x + v.y*v.y + v.z*v.z + v.w*v.w;
    #pragma unroll
    for (int off = 32; off >= 1; off >>= 1) {
        s  += __shfl_down(s,  off, 64);
        sq += __shfl_down(sq, off, 64);
    }
    __shared__ float rs[4], rq[4];
    const int wave = tid >> 6;
    if ((tid & 63) == 0) { rs[wave] = s; rq[wave] = sq; }
    __syncthreads();
    const float tot  = rs[0] + rs[1] + rs[2] + rs[3];
    const float totq = rq[0] + rq[1] + rq[2] + rq[3];
    const float mu   = tot * (1.0f / D_MODEL);
    const float var  = totq * (1.0f / D_MODEL) - mu * mu;
    const float rstd = rsqrtf(var + 1e-5f);
    const float4 gv = ((const float4*)g)[tid];
    const float4 bv = ((const float4*)bb)[tid];
    unsigned short* o = lnout + (size_t)row * D_MODEL + tid * 4;
    o[0] = f2bf((v.x - mu) * rstd * gv.x + bv.x);
    o[1] = f2bf((v.y - mu) * rstd * gv.y + bv.y);
    o[2] = f2bf((v.z - mu) * rstd * gv.z + bv.z);
    o[3] = f2bf((v.w - mu) * rstd * gv.w + bv.w);
}

// ------------- proj split-K reduce: out += bias + p0..p{NP-1} -------------------
template<int NP>
__global__ __launch_bounds__(256) void reduce_kernel(float* __restrict__ out,
                                                     const unsigned short* __restrict__ pp,
                                                     const float* __restrict__ bias) {
    const int row = blockIdx.x;
    const int c0 = threadIdx.x * 4;
    const size_t base = (size_t)row * D_MODEL + c0;
    const size_t stride = (size_t)NROWS * D_MODEL;
    float4 o = *(float4*)(out + base);
    const float4 bs = *(const float4*)(bias + c0);
    o.x += bs.x; o.y += bs.y; o.z += bs.z; o.w += bs.w;
    #pragma unroll
    for (int z = 0; z < NP; ++z) {
        ushort4 a = *(const ushort4*)(pp + z * stride + base);
        o.x += bf2f(a.x); o.y += bf2f(a.y); o.z += bf2f(a.z); o.w += bf2f(a.w);
    }
    *(float4*)(out + base) = o;
}

// ---------------- Flash attention, causal, balanced (paired 128-q tiles) --------
__global__ __launch_bounds__(256) void attn_kernel(const unsigned short* __restrict__ qk,
                                                   const unsigned short* __restrict__ VT,
                                                   unsigned short* __restrict__ y) {
    __shared__ __align__(16) unsigned short Qs[128 * 64];
    __shared__ __align__(16) unsigned short Ks[64 * 64];
    __shared__ __align__(16) unsigned short Vs[80 * 64];
    __shared__ __align__(16) unsigned short Ps[128 * 68];

    const int tid  = threadIdx.x;
    const int lane = tid & 63, w = tid >> 6;
    const int quad = lane >> 4, l16 = lane & 15;
    const int s7   = l16 & 7;
    const int pc0  = (quad ^ s7) * 8;
    const int pc1  = ((quad + 4) ^ s7) * 8;
    const int srow = tid >> 3, sp = tid & 7;

    const int pairidx = blockIdx.x;
    const int bh = blockIdx.y;
    const int b = bh >> 4, h = bh & 15;
    const size_t rowbase = (size_t)b * SEQ;
    const unsigned short* Qbase = qk + h * 64;
    const unsigned short* Kbase = qk + 1024 + h * 64;
    const unsigned short* Vbase = VT + (size_t)(h * 64) * NROWS + b * SEQ;

    #pragma unroll
    for (int e = 0; e < 4; ++e) {
        const int off = tid * 4 + e;
        Vs[4096 + off] = (off < 64) ? (unsigned short)0x3F80 : (unsigned short)0;
    }

    for (int phase = 0; phase < 2; ++phase) {
        const int Q = phase ? pairidx : (15 - pairidx);
        const int nkt = 2 * Q + 2;
        const int qg0 = Q * 128;

        #pragma unroll
        for (int i = 0; i < 4; ++i) {
            const int row = i * 32 + srow;
            const int c = sp ^ (row & 7);
            ASYNC_COPY16(Qbase + (rowbase + qg0 + row) * 2048 + c * 8,
                         (char*)Qs + i * 4096 + tid * 16);
        }
        __syncthreads();

        bf16x8 aq[2][2];
        #pragma unroll
        for (int sub = 0; sub < 2; ++sub) {
            const int qrow = sub * 64 + w * 16 + l16;
            aq[sub][0] = *(const bf16x8*)&Qs[qrow * 64 + pc0];
            aq[sub][1] = *(const bf16x8*)&Qs[qrow * 64 + pc1];
        }

        f32x4 o[2][5] = {};

        for (int kt = 0; kt < nkt; ++kt) {
            #pragma unroll
            for (int i = 0; i < 2; ++i) {
                const int row = i * 32 + srow;
                const int c = sp ^ (row & 7);
                ASYNC_COPY16(Kbase + (rowbase + kt * 64 + row) * 2048 + c * 8,
                             (char*)Ks + i * 4096 + tid * 16);
                ASYNC_COPY16(Vbase + (size_t)row * NROWS + kt * 64 + c * 8,
                             (char*)Vs + i * 4096 + tid * 16);
            }
            __syncthreads();

            bf16x8 bk[4][2];
            #pragma unroll
            for (int cb = 0; cb < 4; ++cb) {
                const int krow = cb * 16 + l16;
                bk[cb][0] = *(const bf16x8*)&Ks[krow * 64 + pc0];
                bk[cb][1] = *(const bf16x8*)&Ks[krow * 64 + pc1];
            }

            #pragma unroll
            for (int sub = 0; sub < 2; ++sub) {
                if (kt > 2 * Q + sub) continue;
                f32x4 s[4] = {};
                #pragma unroll
                for (int cb = 0; cb < 4; ++cb) {
                    s[cb] = __builtin_amdgcn_mfma_f32_16x16x32_bf16(aq[sub][0], bk[cb][0], s[cb], 0, 0, 0);
                    s[cb] = __builtin_amdgcn_mfma_f32_16x16x32_bf16(aq[sub][1], bk[cb][1], s[cb], 0, 0, 0);
                }
                const int prow0 = sub * 64 + w * 16 + quad * 4;
                if (kt == 2 * Q + sub) {
                    const int qg = qg0 + prow0;
                    const int kg = kt * 64 + l16;
                    #pragma unroll
                    for (int cb = 0; cb < 4; ++cb)
                        #pragma unroll
                        for (int r = 0; r < 4; ++r) {
                            const float e = __expf(s[cb][r]);
                            const float pv = (kg + cb * 16 > qg + r) ? 0.0f : e;
                            Ps[(prow0 + r) * 68 + cb * 16 + l16] = f2bf(pv);
                        }
                } else {
                    #pragma unroll
                    for (int cb = 0; cb < 4; ++cb)
                        #pragma unroll
                        for (int r = 0; r < 4; ++r)
                            Ps[(prow0 + r) * 68 + cb * 16 + l16] = f2bf(__expf(s[cb][r]));
                }
            }
            __syncthreads();

            bf16x8 bv[5][2];
            #pragma unroll
            for (int db = 0; db < 5; ++db) {
                const int vrow = db * 16 + l16;
                bv[db][0] = *(const bf16x8*)&Vs[vrow * 64 + pc0];
                bv[db][1] = *(const bf16x8*)&Vs[vrow * 64 + pc1];
            }
            #pragma unroll
            for (int sub = 0; sub < 2; ++sub) {
                if (kt > 2 * Q + sub) continue;
                const unsigned short* pb = &Ps[(sub * 64 + w * 16 + l16) * 68];
                bf16x8 ap0, ap1;
                *(bf16x4*)&ap0       = *(const bf16x4*)(pb + quad * 8);
                *((bf16x4*)&ap0 + 1) = *(const bf16x4*)(pb + quad * 8 + 4);
                *(bf16x4*)&ap1       = *(const bf16x4*)(pb + 32 + quad * 8);
                *((bf16x4*)&ap1 + 1) = *(const bf16x4*)(pb + 32 + quad * 8 + 4);
                #pragma unroll
                for (int db = 0; db < 5; ++db) {
                    o[sub][db] = __builtin_amdgcn_mfma_f32_16x16x32_bf16(ap0, bv[db][0], o[sub][db], 0, 0, 0);
                    o[sub][db] = __builtin_amdgcn_mfma_f32_16x16x32_bf16(ap1, bv[db][1], o[sub][db], 0, 0, 0);
                }
            }
            __syncthreads();
        }

        #pragma unroll
        for (int sub = 0; sub < 2; ++sub)
            #pragma unroll
            for (int r = 0; r < 4; ++r) {
                const float lsum = __shfl(o[sub][4][r], lane & 48);
                const float rinv = 1.0f / lsum;
                const int trow = qg0 + sub * 64 + w * 16 + quad * 4 + r;
                unsigned short* yp = y + (rowbase + trow) * (size_t)D_MODEL + h * 64 + l16;
                #pragma unroll
                for (int db = 0; db < 4; ++db)
                    yp[db * 16] = f2bf(o[sub][db][r] * rinv);
            }
    }
}

extern "C" void kernel_launch(void* const* d_in, const int* in_sizes, int n_in,
                              void* d_out, int out_size, void* d_ws, size_t ws_size,
                              hipStream_t stream) {
    (void)in_sizes; (void)n_in; (void)out_size; (void)ws_size;
    const float* x      = (const float*)d_in[0];
    const float* w_attn = (const float*)d_in[1];
    const float* w_o    = (const float*)d_in[2];
    const float* ln1_g  = (const float*)d_in[3];
    const float* ln1_b  = (const float*)d_in[4];
    const float* ln2_g  = (const float*)d_in[5];
    const float* ln2_b  = (const float*)d_in[6];
    const float* w_fc   = (const float*)d_in[7];
    const float* b_fc   = (const float*)d_in[8];
    const float* w_proj = (const float*)d_in[9];
    const float* b_proj = (const float*)d_in[10];
    float* out = (float*)d_out;

    static bool attr_set = false;
    if (!attr_set) {
        hipFuncSetAttribute(reinterpret_cast<const void*>(&gemm8<0>),
                            hipFuncAttributeMaxDynamicSharedMemorySize, 131072);
        hipFuncSetAttribute(reinterpret_cast<const void*>(&gemm8<1>),
                            hipFuncAttributeMaxDynamicSharedMemorySize, 131072);
        hipFuncSetAttribute(reinterpret_cast<const void*>(&gemm8<2>),
                            hipFuncAttributeMaxDynamicSharedMemorySize, 131072);
        attr_set = true;
    }

    char* ws = (char*)d_ws;
    const size_t MiB = 1048576;
    // Memory map (MiB), phase-ordered:
    //  phase1: ln_buf@0..16 | qkbuf@16..48 | VTbuf@48..64 | wt_attn@64..70 | wt_o@126..128
    //  phase2 (post-attn): pw@16..48 (2x16)
    //  phase3 (post-reduce_wo): wt_fc@48..56 | wt_proj@56..64 | hbuf@64..128
    //  phase4 (post-fc): pp@0..32 (2x16)
    unsigned short* ln_buf  = (unsigned short*)ws;
    unsigned short* qkbuf   = (unsigned short*)(ws + 16 * MiB);
    unsigned short* VTbuf   = (unsigned short*)(ws + 48 * MiB);
    unsigned short* wt_attn = (unsigned short*)(ws + 64 * MiB);
    unsigned short* hbuf    = (unsigned short*)(ws + 64 * MiB);
    unsigned short* wt_o    = (unsigned short*)(ws + 126 * MiB);
    unsigned short* pw      = (unsigned short*)(ws + 16 * MiB);   // 2 x 16 MiB
    unsigned short* wt_fc   = (unsigned short*)(ws + 48 * MiB);
    unsigned short* wt_proj = (unsigned short*)(ws + 56 * MiB);
    unsigned short* pp      = (unsigned short*)ws;                // 2 x 16 MiB

    wt_kernel<<<dim3(3072 / 32, 1024 / 32), 256, 0, stream>>>(w_attn, wt_attn, 1024, 3072);
    wt_kernel<<<dim3(1024 / 32, 1024 / 32), 256, 0, stream>>>(w_o, wt_o, 1024, 1024);

    ln_kernel<<<NROWS, 256, 0, stream>>>(x, ln1_g, ln1_b, ln_buf);

    // merged QKV (256x256 8-phase): Q(scaled)/K -> qkbuf, V -> VTbuf (transposed)
    gemm8<2><<<dim3(NROWS / 256, 3072 / 256), 512, 131072, stream>>>(
        ln_buf, wt_attn, nullptr, qkbuf, VTbuf, NROWS, 3072, 1024, 0);

    attn_kernel<<<dim3(8, BATCH * NHEAD), 256, 0, stream>>>(qkbuf, VTbuf, ln_buf);

    // w_o: split-K=2 partials (256x256 8-phase) -> 256 blocks = 1/CU exactly
    gemm8<1><<<dim3(NROWS / 256, 1024 / 256, 2), 512, 131072, stream>>>(
        ln_buf, wt_o, nullptr, pw, nullptr, NROWS, 1024, 1024, 512);
    // res1 = x + sum(pw) -> d_out ; LN2(res1) -> ln_buf
    reduce_wo_ln2<2><<<NROWS, 256, 0, stream>>>(x, pw, ln2_g, ln2_b, out, ln_buf);

    wt_kernel<<<dim3(4096 / 32, 1024 / 32), 256, 0, stream>>>(w_fc, wt_fc, 1024, 4096);
    wt_kernel<<<dim3(1024 / 32, 4096 / 32), 256, 0, stream>>>(w_proj, wt_proj, 4096, 1024);

    // fc: 256x256 8-phase, gelu+bias fused (grid 512 = exactly 2 rounds at 1/CU)
    gemm8<0><<<dim3(NROWS / 256, 4096 / 256), 512, 131072, stream>>>(
        ln_buf, wt_fc, b_fc, hbuf, nullptr, NROWS, 4096, 1024, 0);

    // proj: 256x256 8-phase, split-K=2 (2048 each), then reduce
    gemm8<1><<<dim3(NROWS / 256, 1024 / 256, 2), 512, 131072, stream>>>(
        hbuf, wt_proj, nullptr, pp, nullptr, NROWS, 1024, 4096, 2048);
    reduce_kernel<2><<<NROWS, 256, 0, stream>>>(out, pp, b_proj);
}